// Round 15
// baseline (43.711 us; speedup 1.0000x reference)
//
#include <hip/hip_runtime.h>

#define DIM     400
#define NENT    14541
#define B       32
#define NCAND   14505
#define NROUND  3627      // ceil(NCAND/4) candidate quads
#define TSTRIPS 256
#define THREADS 256
#define CVTBLK  2841      // ceil(NENT*DIM/8 / 256)

typedef __attribute__((ext_vector_type(2))) _Float16 half2_t;

static __device__ __forceinline__ half2_t bch(unsigned u) {
    return __builtin_bit_cast(half2_t, u);
}
static __device__ __forceinline__ half2_t habs2(half2_t x) {
    unsigned u = __builtin_bit_cast(unsigned, x) & 0x7fff7fffu;
    return __builtin_bit_cast(half2_t, u);
}
static __device__ __forceinline__ unsigned pkh(float x, float y) {
    half2_t h;
    h.x = (_Float16)x;
    h.y = (_Float16)y;
    return __builtin_bit_cast(unsigned, h);
}
static __device__ __forceinline__ float dot2acc(half2_t m, float s) {
#if __has_builtin(__builtin_amdgcn_fdot2)
    const half2_t ones = {(_Float16)1.f, (_Float16)1.f};
    return __builtin_amdgcn_fdot2(m, ones, s, false);
#else
    return s + (float)m.x + (float)m.y;
#endif
}

// ---- merged setup: blocks [0,CVTBLK) convert ent->f16; blocks [CVTBLK,CVTBLK+32) prep q/o/base
__global__ void setup_kernel(const float* __restrict__ ent,
                             const float* __restrict__ relc,
                             const float* __restrict__ relo,
                             const float* __restrict__ onev,
                             const int*   __restrict__ pairs,
                             uint4* __restrict__ ent16,
                             _Float16* __restrict__ q16,
                             _Float16* __restrict__ o16,
                             float* __restrict__ baseg) {
    const int blk = blockIdx.x;
    const int tid = threadIdx.x;
    if (blk < CVTBLK) {
        const int TOT8 = NENT * DIM / 8;   // 727050
        int i = blk * THREADS + tid;
        if (i >= TOT8) return;
        const float4* s4 = (const float4*)ent;
        float4 a = s4[2 * i], c = s4[2 * i + 1];
        uint4 d;
        d.x = pkh(a.x, a.y);
        d.y = pkh(a.z, a.w);
        d.z = pkh(c.x, c.y);
        d.w = pkh(c.z, c.w);
        ent16[i] = d;
    } else {
        const int b = blk - CVTBLK;
        const int h = pairs[2 * b + 0];
        const int r = pairs[2 * b + 1];
        float so = 0.f;
        for (int i = tid; i < DIM; i += THREADS) {
            float qv = ent[(size_t)h * DIM + i] + relc[(size_t)r * DIM + i];
            float ov = relo[(size_t)r * DIM + i];
            q16[(size_t)b * DIM + i] = (_Float16)qv;
            o16[(size_t)b * DIM + i] = (_Float16)(0.98f * ov);
            so += ov;
        }
        __shared__ float sred[4];
        for (int off = 32; off; off >>= 1) so += __shfl_down(so, off);
        if ((tid & 63) == 0) sred[tid >> 6] = so;
        __syncthreads();
        if (tid == 0)
            baseg[b] = onev[0] + 0.98f * (sred[0] + sred[1] + sred[2] + sred[3]);
    }
}

// ---- main (f16, NB=2): wave = 4 cand-slots x 16 dim-lanes; lane u owns uint4-chunks
// u+16k (k=0..2) + tail 48+u (u<2). Each wave holds q/o for TWO batches in registers
// (16 uint4 = 64 VGPR) and computes both against each loaded candidate -> per-output
// VMEM halves, per-round VALU (~640 cyc) covers the ~500-cyc L2-miss/L3 latency
// (cidx gather -> candidate rows are random: no L2 pinning exists; L3 is the server).
__global__ __launch_bounds__(THREADS, 2)
void score_f16(const uint4* __restrict__ ent16,
               const uint4* __restrict__ q16,
               const uint4* __restrict__ o16,
               const float* __restrict__ baseg,
               const int*   __restrict__ cidx,
               float* __restrict__ out) {
    const int fid  = blockIdx.x;
    const int xcd  = fid & 7;
    const int rest = fid >> 3;
    const int beta = rest & 3;           // batch group: batches 8*beta .. 8*beta+7
    const int tc   = rest >> 2;          // 0..31
    const int t    = xcd + 8 * tc;       // strip 0..255

    const int tid  = threadIdx.x;
    const int wid  = tid >> 6;
    const int lane = tid & 63;
    const int u    = lane & 15;
    const int g    = lane >> 4;
    const int b0   = __builtin_amdgcn_readfirstlane(8 * beta + 2 * wid);
    const int b1   = b0 + 1;

    const uint4* qa = q16 + (size_t)b0 * 50;
    const uint4* oa = o16 + (size_t)b0 * 50;
    const uint4* qc = q16 + (size_t)b1 * 50;
    const uint4* oc = o16 + (size_t)b1 * 50;

    uint4 qA[4], oA[4], qB[4], oB[4];
    qA[0] = qa[u]; qA[1] = qa[u + 16]; qA[2] = qa[u + 32];
    oA[0] = oa[u]; oA[1] = oa[u + 16]; oA[2] = oa[u + 32];
    qB[0] = qc[u]; qB[1] = qc[u + 16]; qB[2] = qc[u + 32];
    oB[0] = oc[u]; oB[1] = oc[u + 16]; oB[2] = oc[u + 32];
    qA[3] = qA[0]; oA[3] = oA[0]; qB[3] = qB[0]; oB[3] = oB[0];
    if (u < 2) {
        qA[3] = qa[48 + u]; oA[3] = oa[48 + u];
        qB[3] = qc[48 + u]; oB[3] = oc[48 + u];
    }
    const float baseA = baseg[b0];
    const float baseB = baseg[b1];

    const half2_t K002 = {(_Float16)0.02f, (_Float16)0.02f};

#define PAIR(cu, qu, ou, SS)                                    \
    {                                                           \
        half2_t cc_ = bch(cu), qq_ = bch(qu), oo_ = bch(ou);    \
        half2_t dd_ = cc_ - qq_;                                \
        half2_t aa_ = habs2(dd_);                               \
        half2_t ee_ = aa_ * K002 + oo_;                         \
        half2_t mm_ = __builtin_elementwise_max(aa_, ee_);      \
        SS = dot2acc(mm_, SS);                                  \
    }
#define PROC(C, Q, O, SA, SB)                                   \
    PAIR(C.x, Q.x, O.x, SA) PAIR(C.y, Q.y, O.y, SB)             \
    PAIR(C.z, Q.z, O.z, SA) PAIR(C.w, Q.w, O.w, SB)

    for (int rr = t; rr < NROUND; rr += TSTRIPS) {
        const int cand = 4 * rr + g;
        const int ci   = cidx[cand < NCAND ? cand : NCAND - 1];  // clamp: harmless dup
        const uint4* p = ent16 + (size_t)ci * 50;

        uint4 cv0 = p[u], cv1 = p[u + 16], cv2 = p[u + 32];
        uint4 cv3;
        if (u < 2) cv3 = p[48 + u];

        float sA0 = 0.f, sA1 = 0.f, sB0 = 0.f, sB1 = 0.f;
        PROC(cv0, qA[0], oA[0], sA0, sA1)
        PROC(cv1, qA[1], oA[1], sA0, sA1)
        PROC(cv2, qA[2], oA[2], sA0, sA1)
        PROC(cv0, qB[0], oB[0], sB0, sB1)
        PROC(cv1, qB[1], oB[1], sB0, sB1)
        PROC(cv2, qB[2], oB[2], sB0, sB1)
        if (u < 2) {
            PROC(cv3, qA[3], oA[3], sA0, sA1)
            PROC(cv3, qB[3], oB[3], sB0, sB1)
        }

        float sA = sA0 + sA1;
        float sB = sB0 + sB1;
        sA += __shfl_xor(sA, 1); sB += __shfl_xor(sB, 1);
        sA += __shfl_xor(sA, 2); sB += __shfl_xor(sB, 2);
        sA += __shfl_xor(sA, 4); sB += __shfl_xor(sB, 4);
        sA += __shfl_xor(sA, 8); sB += __shfl_xor(sB, 8);

        if (u == 0 && cand < NCAND) {
            out[(size_t)b0 * NCAND + cand] = baseA - sA;
            out[(size_t)b1 * NCAND + cand] = baseB - sB;
        }
    }
#undef PROC
#undef PAIR
}

// ---- fallback (no ws): R9 f32 kernel verbatim ----
__global__ __launch_bounds__(THREADS, 2)
void score_f32(const float* __restrict__ ent,
               const float* __restrict__ relc,
               const float* __restrict__ relo,
               const float* __restrict__ onev,
               const int*   __restrict__ pairs,
               const int*   __restrict__ cidx,
               float* __restrict__ out) {
    const int fid  = blockIdx.x;
    const int xcd  = fid & 7;
    const int rest = fid >> 3;
    const int bq   = rest & 7;
    const int tc   = rest >> 3;
    const int t    = xcd + 8 * tc;

    const int tid  = threadIdx.x;
    const int lane = tid & 63;
    const int u    = lane & 15;
    const int g    = lane >> 4;
    const int b    = __builtin_amdgcn_readfirstlane(bq * 4 + (tid >> 6));

    const int hd = pairs[b * 2 + 0];
    const int rl = pairs[b * 2 + 1];
    const float4* hb = (const float4*)(ent  + (size_t)hd * DIM) + u;
    const float4* cb = (const float4*)(relc + (size_t)rl * DIM) + u;
    const float4* ob = (const float4*)(relo + (size_t)rl * DIM) + u;

    float4 q[7], o[7];
    float oa = 0.f;
#pragma unroll
    for (int k = 0; k < 6; ++k) {
        float4 h = hb[16 * k], c = cb[16 * k];
        q[k] = make_float4(h.x + c.x, h.y + c.y, h.z + c.z, h.w + c.w);
        o[k] = ob[16 * k];
        oa += o[k].x + o[k].y + o[k].z + o[k].w;
    }
    if (u < 4) {
        float4 h = hb[96], c = cb[96];
        q[6] = make_float4(h.x + c.x, h.y + c.y, h.z + c.z, h.w + c.w);
        o[6] = ob[96];
        oa += o[6].x + o[6].y + o[6].z + o[6].w;
    }
    oa += __shfl_xor(oa, 1);
    oa += __shfl_xor(oa, 2);
    oa += __shfl_xor(oa, 4);
    oa += __shfl_xor(oa, 8);
    const float base = onev[0] + 0.98f * oa;

    const float4* entu = (const float4*)ent + u;

#define E(vc, vq, vo, AM, AD)                     \
        {                                         \
            float d_ = (vc) - (vq);               \
            AM += fmaxf(fabsf(d_), (vo));         \
            AD += fabsf(d_);                      \
        }
#define F4(k, AM, AD)                             \
        E(cbuf[k].x, q[k].x, o[k].x, AM, AD)      \
        E(cbuf[k].y, q[k].y, o[k].y, AM, AD)      \
        E(cbuf[k].z, q[k].z, o[k].z, AM, AD)      \
        E(cbuf[k].w, q[k].w, o[k].w, AM, AD)

    for (int rr = t; rr < NROUND; rr += TSTRIPS) {
        const int cand = 4 * rr + g;
        const int ci   = cidx[cand < NCAND ? cand : NCAND - 1];
        const float4* p = entu + (size_t)ci * 100;

        float4 cbuf[7];
#pragma unroll
        for (int k = 0; k < 6; ++k) cbuf[k] = p[16 * k];
        if (u < 4) cbuf[6] = p[96];

        float am0 = 0.f, ad0 = 0.f, am1 = 0.f, ad1 = 0.f;
        F4(0, am0, ad0) F4(1, am1, ad1)
        F4(2, am0, ad0) F4(3, am1, ad1)
        F4(4, am0, ad0) F4(5, am1, ad1)
        if (u < 4) { F4(6, am0, ad0) }

        float s_ = fmaf(-0.98f, am0 + am1, -0.02f * (ad0 + ad1));
        s_ += __shfl_xor(s_, 1);
        s_ += __shfl_xor(s_, 2);
        s_ += __shfl_xor(s_, 4);
        s_ += __shfl_xor(s_, 8);

        if (u == 0 && cand < NCAND)
            out[(size_t)b * NCAND + cand] = base + s_;
    }
#undef F4
#undef E
}

extern "C" void kernel_launch(void* const* d_in, const int* in_sizes, int n_in,
                              void* d_out, int out_size, void* d_ws, size_t ws_size,
                              hipStream_t stream) {
    const float* ent   = (const float*)d_in[0];
    const float* relc  = (const float*)d_in[1];
    const float* relo  = (const float*)d_in[2];
    const float* onev  = (const float*)d_in[3];
    const int*   pairs = (const int*)d_in[4];
    const int*   cidx  = (const int*)d_in[5];
    float*       out   = (float*)d_out;

    const size_t entB = (size_t)NENT * DIM * 2;      // 11,632,800 (16B-aligned)
    const size_t qB   = (size_t)B * DIM * 2;         // 25,600
    const size_t need = entB + 2 * qB + B * sizeof(float);

    if (ws_size >= need) {
        unsigned char* w = (unsigned char*)d_ws;
        uint4*    ent16 = (uint4*)w;
        _Float16* q16   = (_Float16*)(w + entB);
        _Float16* o16   = (_Float16*)(w + entB + qB);
        float*    baseg = (float*)(w + entB + 2 * qB);

        setup_kernel<<<CVTBLK + B, THREADS, 0, stream>>>(
            ent, relc, relo, onev, pairs, ent16, q16, o16, baseg);
        score_f16<<<8 * 4 * 32, THREADS, 0, stream>>>(   // 1024 blocks
            ent16, (const uint4*)q16, (const uint4*)o16, baseg, cidx, out);
    } else {
        score_f32<<<8 * 8 * 32, THREADS, 0, stream>>>(   // 2048 blocks
            ent, relc, relo, onev, pairs, cidx, out);
    }
}

// Round 16
// 42.197 us; speedup vs baseline: 1.0359x; 1.0359x over previous
//
#include <hip/hip_runtime.h>

#define DIM     400
#define NENT    14541
#define B       32
#define NCAND   14505
#define NROUND  3627      // ceil(NCAND/4) candidate quads
#define TSTRIPS 256
#define THREADS 256
#define CVTBLK  2841      // ceil(NENT*DIM/8 / 256)

typedef __attribute__((ext_vector_type(2))) _Float16 half2_t;

static __device__ __forceinline__ half2_t bch(unsigned u) {
    return __builtin_bit_cast(half2_t, u);
}
static __device__ __forceinline__ half2_t habs2(half2_t x) {
    unsigned u = __builtin_bit_cast(unsigned, x) & 0x7fff7fffu;
    return __builtin_bit_cast(half2_t, u);
}
static __device__ __forceinline__ unsigned pkh(float x, float y) {
    half2_t h;
    h.x = (_Float16)x;
    h.y = (_Float16)y;
    return __builtin_bit_cast(unsigned, h);
}
static __device__ __forceinline__ float dot2acc(half2_t m, float s) {
#if __has_builtin(__builtin_amdgcn_fdot2)
    const half2_t ones = {(_Float16)1.f, (_Float16)1.f};
    return __builtin_amdgcn_fdot2(m, ones, s, false);
#else
    return s + (float)m.x + (float)m.y;
#endif
}

// ---- merged setup: blocks [0,CVTBLK) convert ent->f16; blocks [CVTBLK,CVTBLK+32) prep q/o/base
__global__ void setup_kernel(const float* __restrict__ ent,
                             const float* __restrict__ relc,
                             const float* __restrict__ relo,
                             const float* __restrict__ onev,
                             const int*   __restrict__ pairs,
                             uint4* __restrict__ ent16,
                             _Float16* __restrict__ q16,
                             _Float16* __restrict__ o16,
                             float* __restrict__ baseg) {
    const int blk = blockIdx.x;
    const int tid = threadIdx.x;
    if (blk < CVTBLK) {
        const int TOT8 = NENT * DIM / 8;   // 727050
        int i = blk * THREADS + tid;
        if (i >= TOT8) return;
        const float4* s4 = (const float4*)ent;
        float4 a = s4[2 * i], c = s4[2 * i + 1];
        uint4 d;
        d.x = pkh(a.x, a.y);
        d.y = pkh(a.z, a.w);
        d.z = pkh(c.x, c.y);
        d.w = pkh(c.z, c.w);
        ent16[i] = d;
    } else {
        const int b = blk - CVTBLK;
        const int h = pairs[2 * b + 0];
        const int r = pairs[2 * b + 1];
        float so = 0.f;
        for (int i = tid; i < DIM; i += THREADS) {
            float qv = ent[(size_t)h * DIM + i] + relc[(size_t)r * DIM + i];
            float ov = relo[(size_t)r * DIM + i];
            q16[(size_t)b * DIM + i] = (_Float16)qv;
            o16[(size_t)b * DIM + i] = (_Float16)(0.98f * ov);
            so += ov;
        }
        __shared__ float sred[4];
        for (int off = 32; off; off >>= 1) so += __shfl_down(so, off);
        if ((tid & 63) == 0) sred[tid >> 6] = so;
        __syncthreads();
        if (tid == 0)
            baseg[b] = onev[0] + 0.98f * (sred[0] + sred[1] + sred[2] + sred[3]);
    }
}

// ---- main (f16, 2 quad-streams x 2 batches): wave = 4 cand-slots x 16 dim-lanes;
// lane u owns uint4-chunks u+16k (k=0..2) + tail 48+u (u<2).
// Per round: load 8 candidate rows (quads rr, rr+256), compute each against TWO
// register-resident batches (q/o = 64 VGPR). 250 VALU per 8 loads -> candidate
// lines per output halved vs R14; stream-A compute covers stream-B load latency.
__global__ __launch_bounds__(THREADS, 2)
void score_f16(const uint4* __restrict__ ent16,
               const uint4* __restrict__ q16,
               const uint4* __restrict__ o16,
               const float* __restrict__ baseg,
               const int*   __restrict__ cidx,
               float* __restrict__ out) {
    const int fid  = blockIdx.x;
    const int xcd  = fid & 7;
    const int rest = fid >> 3;
    const int beta = rest & 3;           // batch group: batches 8*beta .. 8*beta+7
    const int tc   = rest >> 2;          // 0..31
    const int t    = xcd + 8 * tc;       // strip 0..255

    const int tid  = threadIdx.x;
    const int wid  = tid >> 6;
    const int lane = tid & 63;
    const int u    = lane & 15;
    const int g    = lane >> 4;
    const int b0   = __builtin_amdgcn_readfirstlane(8 * beta + 2 * wid);
    const int b1   = b0 + 1;

    const uint4* qa = q16 + (size_t)b0 * 50;
    const uint4* oa = o16 + (size_t)b0 * 50;
    const uint4* qc = q16 + (size_t)b1 * 50;
    const uint4* oc = o16 + (size_t)b1 * 50;

    uint4 q0[4], o0[4], q1[4], o1[4];
    q0[0] = qa[u]; q0[1] = qa[u + 16]; q0[2] = qa[u + 32];
    o0[0] = oa[u]; o0[1] = oa[u + 16]; o0[2] = oa[u + 32];
    q1[0] = qc[u]; q1[1] = qc[u + 16]; q1[2] = qc[u + 32];
    o1[0] = oc[u]; o1[1] = oc[u + 16]; o1[2] = oc[u + 32];
    q0[3] = q0[0]; o0[3] = o0[0]; q1[3] = q1[0]; o1[3] = o1[0];
    if (u < 2) {
        q0[3] = qa[48 + u]; o0[3] = oa[48 + u];
        q1[3] = qc[48 + u]; o1[3] = oc[48 + u];
    }
    const float base0 = baseg[b0];
    const float base1 = baseg[b1];

    const half2_t K002 = {(_Float16)0.02f, (_Float16)0.02f};

#define PAIR(cu, qu, ou, SS)                                    \
    {                                                           \
        half2_t cc_ = bch(cu), qq_ = bch(qu), oo_ = bch(ou);    \
        half2_t dd_ = cc_ - qq_;                                \
        half2_t aa_ = habs2(dd_);                               \
        half2_t ee_ = aa_ * K002 + oo_;                         \
        half2_t mm_ = __builtin_elementwise_max(aa_, ee_);      \
        SS = dot2acc(mm_, SS);                                  \
    }
#define PROC(C, Q, O, SA, SB)                                   \
    PAIR(C.x, Q.x, O.x, SA) PAIR(C.y, Q.y, O.y, SB)             \
    PAIR(C.z, Q.z, O.z, SA) PAIR(C.w, Q.w, O.w, SB)

    for (int rr = t; rr < NROUND; rr += 2 * TSTRIPS) {
        const int rr2   = rr + TSTRIPS;
        const int candA = 4 * rr + g;
        const int candB = 4 * rr2 + g;
        const int ciA = cidx[candA < NCAND ? candA : NCAND - 1];
        const int ciB = cidx[candB < NCAND ? candB : NCAND - 1];
        const uint4* pA = ent16 + (size_t)ciA * 50;
        const uint4* pB = ent16 + (size_t)ciB * 50;

        uint4 av0 = pA[u], av1 = pA[u + 16], av2 = pA[u + 32];
        uint4 bv0 = pB[u], bv1 = pB[u + 16], bv2 = pB[u + 32];
        uint4 av3, bv3;
        if (u < 2) { av3 = pA[48 + u]; bv3 = pB[48 + u]; }

        // 8 accumulator chains: {quadA,quadB} x {batch0,batch1} x {2 chains}
        float sA00 = 0.f, sA01 = 0.f, sA10 = 0.f, sA11 = 0.f;
        float sB00 = 0.f, sB01 = 0.f, sB10 = 0.f, sB11 = 0.f;

        // quad-stream A first (stream B's loads keep flying under this compute)
        PROC(av0, q0[0], o0[0], sA00, sA01)
        PROC(av1, q0[1], o0[1], sA00, sA01)
        PROC(av2, q0[2], o0[2], sA00, sA01)
        PROC(av0, q1[0], o1[0], sA10, sA11)
        PROC(av1, q1[1], o1[1], sA10, sA11)
        PROC(av2, q1[2], o1[2], sA10, sA11)
        if (u < 2) {
            PROC(av3, q0[3], o0[3], sA00, sA01)
            PROC(av3, q1[3], o1[3], sA10, sA11)
        }
        // quad-stream B
        PROC(bv0, q0[0], o0[0], sB00, sB01)
        PROC(bv1, q0[1], o0[1], sB00, sB01)
        PROC(bv2, q0[2], o0[2], sB00, sB01)
        PROC(bv0, q1[0], o1[0], sB10, sB11)
        PROC(bv1, q1[1], o1[1], sB10, sB11)
        PROC(bv2, q1[2], o1[2], sB10, sB11)
        if (u < 2) {
            PROC(bv3, q0[3], o0[3], sB00, sB01)
            PROC(bv3, q1[3], o1[3], sB10, sB11)
        }

        float sA0 = sA00 + sA01;   // quadA batch0
        float sA1 = sA10 + sA11;   // quadA batch1
        float sB0 = sB00 + sB01;   // quadB batch0
        float sB1 = sB10 + sB11;   // quadB batch1
        sA0 += __shfl_xor(sA0, 1); sA1 += __shfl_xor(sA1, 1);
        sB0 += __shfl_xor(sB0, 1); sB1 += __shfl_xor(sB1, 1);
        sA0 += __shfl_xor(sA0, 2); sA1 += __shfl_xor(sA1, 2);
        sB0 += __shfl_xor(sB0, 2); sB1 += __shfl_xor(sB1, 2);
        sA0 += __shfl_xor(sA0, 4); sA1 += __shfl_xor(sA1, 4);
        sB0 += __shfl_xor(sB0, 4); sB1 += __shfl_xor(sB1, 4);
        sA0 += __shfl_xor(sA0, 8); sA1 += __shfl_xor(sA1, 8);
        sB0 += __shfl_xor(sB0, 8); sB1 += __shfl_xor(sB1, 8);

        if (u == 0) {
            if (candA < NCAND) {
                out[(size_t)b0 * NCAND + candA] = base0 - sA0;
                out[(size_t)b1 * NCAND + candA] = base1 - sA1;
            }
            if (candB < NCAND) {
                out[(size_t)b0 * NCAND + candB] = base0 - sB0;
                out[(size_t)b1 * NCAND + candB] = base1 - sB1;
            }
        }
    }
#undef PROC
#undef PAIR
}

// ---- fallback (no ws): R9 f32 kernel verbatim ----
__global__ __launch_bounds__(THREADS, 2)
void score_f32(const float* __restrict__ ent,
               const float* __restrict__ relc,
               const float* __restrict__ relo,
               const float* __restrict__ onev,
               const int*   __restrict__ pairs,
               const int*   __restrict__ cidx,
               float* __restrict__ out) {
    const int fid  = blockIdx.x;
    const int xcd  = fid & 7;
    const int rest = fid >> 3;
    const int bq   = rest & 7;
    const int tc   = rest >> 3;
    const int t    = xcd + 8 * tc;

    const int tid  = threadIdx.x;
    const int lane = tid & 63;
    const int u    = lane & 15;
    const int g    = lane >> 4;
    const int b    = __builtin_amdgcn_readfirstlane(bq * 4 + (tid >> 6));

    const int hd = pairs[b * 2 + 0];
    const int rl = pairs[b * 2 + 1];
    const float4* hb = (const float4*)(ent  + (size_t)hd * DIM) + u;
    const float4* cb = (const float4*)(relc + (size_t)rl * DIM) + u;
    const float4* ob = (const float4*)(relo + (size_t)rl * DIM) + u;

    float4 q[7], o[7];
    float oa = 0.f;
#pragma unroll
    for (int k = 0; k < 6; ++k) {
        float4 h = hb[16 * k], c = cb[16 * k];
        q[k] = make_float4(h.x + c.x, h.y + c.y, h.z + c.z, h.w + c.w);
        o[k] = ob[16 * k];
        oa += o[k].x + o[k].y + o[k].z + o[k].w;
    }
    if (u < 4) {
        float4 h = hb[96], c = cb[96];
        q[6] = make_float4(h.x + c.x, h.y + c.y, h.z + c.z, h.w + c.w);
        o[6] = ob[96];
        oa += o[6].x + o[6].y + o[6].z + o[6].w;
    }
    oa += __shfl_xor(oa, 1);
    oa += __shfl_xor(oa, 2);
    oa += __shfl_xor(oa, 4);
    oa += __shfl_xor(oa, 8);
    const float base = onev[0] + 0.98f * oa;

    const float4* entu = (const float4*)ent + u;

#define E(vc, vq, vo, AM, AD)                     \
        {                                         \
            float d_ = (vc) - (vq);               \
            AM += fmaxf(fabsf(d_), (vo));         \
            AD += fabsf(d_);                      \
        }
#define F4(k, AM, AD)                             \
        E(cbuf[k].x, q[k].x, o[k].x, AM, AD)      \
        E(cbuf[k].y, q[k].y, o[k].y, AM, AD)      \
        E(cbuf[k].z, q[k].z, o[k].z, AM, AD)      \
        E(cbuf[k].w, q[k].w, o[k].w, AM, AD)

    for (int rr = t; rr < NROUND; rr += TSTRIPS) {
        const int cand = 4 * rr + g;
        const int ci   = cidx[cand < NCAND ? cand : NCAND - 1];
        const float4* p = entu + (size_t)ci * 100;

        float4 cbuf[7];
#pragma unroll
        for (int k = 0; k < 6; ++k) cbuf[k] = p[16 * k];
        if (u < 4) cbuf[6] = p[96];

        float am0 = 0.f, ad0 = 0.f, am1 = 0.f, ad1 = 0.f;
        F4(0, am0, ad0) F4(1, am1, ad1)
        F4(2, am0, ad0) F4(3, am1, ad1)
        F4(4, am0, ad0) F4(5, am1, ad1)
        if (u < 4) { F4(6, am0, ad0) }

        float s_ = fmaf(-0.98f, am0 + am1, -0.02f * (ad0 + ad1));
        s_ += __shfl_xor(s_, 1);
        s_ += __shfl_xor(s_, 2);
        s_ += __shfl_xor(s_, 4);
        s_ += __shfl_xor(s_, 8);

        if (u == 0 && cand < NCAND)
            out[(size_t)b * NCAND + cand] = base + s_;
    }
#undef F4
#undef E
}

extern "C" void kernel_launch(void* const* d_in, const int* in_sizes, int n_in,
                              void* d_out, int out_size, void* d_ws, size_t ws_size,
                              hipStream_t stream) {
    const float* ent   = (const float*)d_in[0];
    const float* relc  = (const float*)d_in[1];
    const float* relo  = (const float*)d_in[2];
    const float* onev  = (const float*)d_in[3];
    const int*   pairs = (const int*)d_in[4];
    const int*   cidx  = (const int*)d_in[5];
    float*       out   = (float*)d_out;

    const size_t entB = (size_t)NENT * DIM * 2;      // 11,632,800 (16B-aligned)
    const size_t qB   = (size_t)B * DIM * 2;         // 25,600
    const size_t need = entB + 2 * qB + B * sizeof(float);

    if (ws_size >= need) {
        unsigned char* w = (unsigned char*)d_ws;
        uint4*    ent16 = (uint4*)w;
        _Float16* q16   = (_Float16*)(w + entB);
        _Float16* o16   = (_Float16*)(w + entB + qB);
        float*    baseg = (float*)(w + entB + 2 * qB);

        setup_kernel<<<CVTBLK + B, THREADS, 0, stream>>>(
            ent, relc, relo, onev, pairs, ent16, q16, o16, baseg);
        score_f16<<<8 * 4 * 32, THREADS, 0, stream>>>(   // 1024 blocks, all-resident
            ent16, (const uint4*)q16, (const uint4*)o16, baseg, cidx, out);
    } else {
        score_f32<<<8 * 8 * 32, THREADS, 0, stream>>>(   // 2048 blocks
            ent, relc, relo, onev, pairs, cidx, out);
    }
}

// Round 17
// 39.838 us; speedup vs baseline: 1.0972x; 1.0592x over previous
//
#include <hip/hip_runtime.h>

#define DIM     400
#define NENT    14541
#define B       32
#define NCAND   14505
#define NROUND  3627      // ceil(NCAND/4) candidate quads
#define NSTRIPS 256
#define THREADS 256
#define DROWS   14508     // 4*NROUND rows in dense table
#define CVTN    (DROWS * 50)            // 725400 uint4 writes
#define CVTBLK  ((CVTN + THREADS - 1) / THREADS)   // 2834

typedef __attribute__((ext_vector_type(2))) _Float16 half2_t;

static __device__ __forceinline__ half2_t bch(unsigned u) {
    return __builtin_bit_cast(half2_t, u);
}
static __device__ __forceinline__ half2_t habs2(half2_t x) {
    unsigned u = __builtin_bit_cast(unsigned, x) & 0x7fff7fffu;
    return __builtin_bit_cast(half2_t, u);
}
static __device__ __forceinline__ unsigned pkh(float x, float y) {
    half2_t h;
    h.x = (_Float16)x;
    h.y = (_Float16)y;
    return __builtin_bit_cast(unsigned, h);
}
static __device__ __forceinline__ float dot2acc(half2_t m, float s) {
#if __has_builtin(__builtin_amdgcn_fdot2)
    const half2_t ones = {(_Float16)1.f, (_Float16)1.f};
    return __builtin_amdgcn_fdot2(m, ones, s, false);
#else
    return s + (float)m.x + (float)m.y;
#endif
}

// ---- merged setup ----
// blocks [0,CVTBLK): dense16[n] = f16(ent[cidx[n]]) — gather ONCE, so score streams
// sequentially. blocks [CVTBLK, CVTBLK+32): q16/o16/base prep.
__global__ void setup_kernel(const float* __restrict__ ent,
                             const float* __restrict__ relc,
                             const float* __restrict__ relo,
                             const float* __restrict__ onev,
                             const int*   __restrict__ pairs,
                             const int*   __restrict__ cidx,
                             uint4* __restrict__ dense16,
                             _Float16* __restrict__ q16,
                             _Float16* __restrict__ o16,
                             float* __restrict__ baseg) {
    const int blk = blockIdx.x;
    const int tid = threadIdx.x;
    if (blk < CVTBLK) {
        int i = blk * THREADS + tid;              // uint4 index: row*50 + col
        if (i >= CVTN) return;
        int row = i / 50;
        int col = i - row * 50;
        int n  = row < NCAND ? row : NCAND - 1;   // pad rows duplicate last cand
        int ci = cidx[n];
        const float4* s4 = (const float4*)(ent + (size_t)ci * DIM) + col * 2;
        float4 a = s4[0], c = s4[1];
        uint4 d;
        d.x = pkh(a.x, a.y);
        d.y = pkh(a.z, a.w);
        d.z = pkh(c.x, c.y);
        d.w = pkh(c.z, c.w);
        dense16[i] = d;
    } else {
        const int b = blk - CVTBLK;
        const int h = pairs[2 * b + 0];
        const int r = pairs[2 * b + 1];
        float so = 0.f;
        for (int i = tid; i < DIM; i += THREADS) {
            float qv = ent[(size_t)h * DIM + i] + relc[(size_t)r * DIM + i];
            float ov = relo[(size_t)r * DIM + i];
            q16[(size_t)b * DIM + i] = (_Float16)qv;
            o16[(size_t)b * DIM + i] = (_Float16)(0.98f * ov);
            so += ov;
        }
        __shared__ float sred[4];
        for (int off = 32; off; off >>= 1) so += __shfl_down(so, off);
        if ((tid & 63) == 0) sred[tid >> 6] = so;
        __syncthreads();
        if (tid == 0)
            baseg[b] = onev[0] + 0.98f * (sred[0] + sred[1] + sred[2] + sred[3]);
    }
}

// ---- main (f16, dense stream, 2 quad-streams x 2 batches) ----
// Strip s owns a CONTIGUOUS round range (14 or 15 rounds, zero idle). The 4
// beta-blocks of a strip share one XCD (fid%8 == xcd for all); each XCD touches
// ~1.5 MB of dense16 -> L2-resident sequential stream (~200cy) replaces the
// random L3 gather (~600cy) that was the R14-R16 invariant cost.
__global__ __launch_bounds__(THREADS, 2)
void score_f16(const uint4* __restrict__ dense16,
               const uint4* __restrict__ q16,
               const uint4* __restrict__ o16,
               const float* __restrict__ baseg,
               float* __restrict__ out) {
    const int fid  = blockIdx.x;
    const int xcd  = fid & 7;
    const int rest = fid >> 3;
    const int beta = rest & 3;           // batch group: batches 8*beta .. 8*beta+7
    const int tc   = rest >> 2;          // 0..31
    const int strip = xcd + 8 * tc;      // 0..255; all 4 beta-blocks same XCD

    // balanced contiguous range: strips 0..42 get 15 rounds, rest 14
    const int r0 = strip * 14 + (strip < 43 ? strip : 43);
    const int r1 = r0 + 14 + (strip < 43 ? 1 : 0);

    const int tid  = threadIdx.x;
    const int wid  = tid >> 6;
    const int lane = tid & 63;
    const int u    = lane & 15;
    const int g    = lane >> 4;
    const int b0   = __builtin_amdgcn_readfirstlane(8 * beta + 2 * wid);
    const int b1   = b0 + 1;

    const uint4* qa = q16 + (size_t)b0 * 50;
    const uint4* oa = o16 + (size_t)b0 * 50;
    const uint4* qc = q16 + (size_t)b1 * 50;
    const uint4* oc = o16 + (size_t)b1 * 50;

    uint4 q0[4], o0[4], q1[4], o1[4];
    q0[0] = qa[u]; q0[1] = qa[u + 16]; q0[2] = qa[u + 32];
    o0[0] = oa[u]; o0[1] = oa[u + 16]; o0[2] = oa[u + 32];
    q1[0] = qc[u]; q1[1] = qc[u + 16]; q1[2] = qc[u + 32];
    o1[0] = oc[u]; o1[1] = oc[u + 16]; o1[2] = oc[u + 32];
    q0[3] = q0[0]; o0[3] = o0[0]; q1[3] = q1[0]; o1[3] = o1[0];
    if (u < 2) {
        q0[3] = qa[48 + u]; o0[3] = oa[48 + u];
        q1[3] = qc[48 + u]; o1[3] = oc[48 + u];
    }
    const float base0 = baseg[b0];
    const float base1 = baseg[b1];

    const half2_t K002 = {(_Float16)0.02f, (_Float16)0.02f};

#define PAIR(cu, qu, ou, SS)                                    \
    {                                                           \
        half2_t cc_ = bch(cu), qq_ = bch(qu), oo_ = bch(ou);    \
        half2_t dd_ = cc_ - qq_;                                \
        half2_t aa_ = habs2(dd_);                               \
        half2_t ee_ = aa_ * K002 + oo_;                         \
        half2_t mm_ = __builtin_elementwise_max(aa_, ee_);      \
        SS = dot2acc(mm_, SS);                                  \
    }
#define PROC(C, Q, O, SA, SB)                                   \
    PAIR(C.x, Q.x, O.x, SA) PAIR(C.y, Q.y, O.y, SB)             \
    PAIR(C.z, Q.z, O.z, SA) PAIR(C.w, Q.w, O.w, SB)

    for (int rr = r0; rr < r1; rr += 2) {
        const int rA = rr;
        const int rB = (rr + 1 < r1) ? rr + 1 : rr;   // odd tail: dup A (no B store)
        const uint4* pA = dense16 + (size_t)(4 * rA + g) * 50;
        const uint4* pB = dense16 + (size_t)(4 * rB + g) * 50;

        uint4 av0 = pA[u], av1 = pA[u + 16], av2 = pA[u + 32];
        uint4 bv0 = pB[u], bv1 = pB[u + 16], bv2 = pB[u + 32];
        uint4 av3, bv3;
        if (u < 2) { av3 = pA[48 + u]; bv3 = pB[48 + u]; }

        float sA00 = 0.f, sA01 = 0.f, sA10 = 0.f, sA11 = 0.f;
        float sB00 = 0.f, sB01 = 0.f, sB10 = 0.f, sB11 = 0.f;

        PROC(av0, q0[0], o0[0], sA00, sA01)
        PROC(av1, q0[1], o0[1], sA00, sA01)
        PROC(av2, q0[2], o0[2], sA00, sA01)
        PROC(av0, q1[0], o1[0], sA10, sA11)
        PROC(av1, q1[1], o1[1], sA10, sA11)
        PROC(av2, q1[2], o1[2], sA10, sA11)
        if (u < 2) {
            PROC(av3, q0[3], o0[3], sA00, sA01)
            PROC(av3, q1[3], o1[3], sA10, sA11)
        }
        PROC(bv0, q0[0], o0[0], sB00, sB01)
        PROC(bv1, q0[1], o0[1], sB00, sB01)
        PROC(bv2, q0[2], o0[2], sB00, sB01)
        PROC(bv0, q1[0], o1[0], sB10, sB11)
        PROC(bv1, q1[1], o1[1], sB10, sB11)
        PROC(bv2, q1[2], o1[2], sB10, sB11)
        if (u < 2) {
            PROC(bv3, q0[3], o0[3], sB00, sB01)
            PROC(bv3, q1[3], o1[3], sB10, sB11)
        }

        float sA0 = sA00 + sA01;
        float sA1 = sA10 + sA11;
        float sB0 = sB00 + sB01;
        float sB1 = sB10 + sB11;
        sA0 += __shfl_xor(sA0, 1); sA1 += __shfl_xor(sA1, 1);
        sB0 += __shfl_xor(sB0, 1); sB1 += __shfl_xor(sB1, 1);
        sA0 += __shfl_xor(sA0, 2); sA1 += __shfl_xor(sA1, 2);
        sB0 += __shfl_xor(sB0, 2); sB1 += __shfl_xor(sB1, 2);
        sA0 += __shfl_xor(sA0, 4); sA1 += __shfl_xor(sA1, 4);
        sB0 += __shfl_xor(sB0, 4); sB1 += __shfl_xor(sB1, 4);
        sA0 += __shfl_xor(sA0, 8); sA1 += __shfl_xor(sA1, 8);
        sB0 += __shfl_xor(sB0, 8); sB1 += __shfl_xor(sB1, 8);

        if (u == 0) {
            const int candA = 4 * rA + g;
            const int candB = 4 * rB + g;
            if (candA < NCAND) {
                out[(size_t)b0 * NCAND + candA] = base0 - sA0;
                out[(size_t)b1 * NCAND + candA] = base1 - sA1;
            }
            if (rB != rA && candB < NCAND) {
                out[(size_t)b0 * NCAND + candB] = base0 - sB0;
                out[(size_t)b1 * NCAND + candB] = base1 - sB1;
            }
        }
    }
#undef PROC
#undef PAIR
}

// ---- fallback (no ws): R9 f32 kernel verbatim ----
__global__ __launch_bounds__(THREADS, 2)
void score_f32(const float* __restrict__ ent,
               const float* __restrict__ relc,
               const float* __restrict__ relo,
               const float* __restrict__ onev,
               const int*   __restrict__ pairs,
               const int*   __restrict__ cidx,
               float* __restrict__ out) {
    const int fid  = blockIdx.x;
    const int xcd  = fid & 7;
    const int rest = fid >> 3;
    const int bq   = rest & 7;
    const int tc   = rest >> 3;
    const int t    = xcd + 8 * tc;

    const int tid  = threadIdx.x;
    const int lane = tid & 63;
    const int u    = lane & 15;
    const int g    = lane >> 4;
    const int b    = __builtin_amdgcn_readfirstlane(bq * 4 + (tid >> 6));

    const int hd = pairs[b * 2 + 0];
    const int rl = pairs[b * 2 + 1];
    const float4* hb = (const float4*)(ent  + (size_t)hd * DIM) + u;
    const float4* cb = (const float4*)(relc + (size_t)rl * DIM) + u;
    const float4* ob = (const float4*)(relo + (size_t)rl * DIM) + u;

    float4 q[7], o[7];
    float oa = 0.f;
#pragma unroll
    for (int k = 0; k < 6; ++k) {
        float4 h = hb[16 * k], c = cb[16 * k];
        q[k] = make_float4(h.x + c.x, h.y + c.y, h.z + c.z, h.w + c.w);
        o[k] = ob[16 * k];
        oa += o[k].x + o[k].y + o[k].z + o[k].w;
    }
    if (u < 4) {
        float4 h = hb[96], c = cb[96];
        q[6] = make_float4(h.x + c.x, h.y + c.y, h.z + c.z, h.w + c.w);
        o[6] = ob[96];
        oa += o[6].x + o[6].y + o[6].z + o[6].w;
    }
    oa += __shfl_xor(oa, 1);
    oa += __shfl_xor(oa, 2);
    oa += __shfl_xor(oa, 4);
    oa += __shfl_xor(oa, 8);
    const float base = onev[0] + 0.98f * oa;

    const float4* entu = (const float4*)ent + u;

#define E(vc, vq, vo, AM, AD)                     \
        {                                         \
            float d_ = (vc) - (vq);               \
            AM += fmaxf(fabsf(d_), (vo));         \
            AD += fabsf(d_);                      \
        }
#define F4(k, AM, AD)                             \
        E(cbuf[k].x, q[k].x, o[k].x, AM, AD)      \
        E(cbuf[k].y, q[k].y, o[k].y, AM, AD)      \
        E(cbuf[k].z, q[k].z, o[k].z, AM, AD)      \
        E(cbuf[k].w, q[k].w, o[k].w, AM, AD)

    for (int rr = t; rr < NROUND; rr += NSTRIPS) {
        const int cand = 4 * rr + g;
        const int ci   = cidx[cand < NCAND ? cand : NCAND - 1];
        const float4* p = entu + (size_t)ci * 100;

        float4 cbuf[7];
#pragma unroll
        for (int k = 0; k < 6; ++k) cbuf[k] = p[16 * k];
        if (u < 4) cbuf[6] = p[96];

        float am0 = 0.f, ad0 = 0.f, am1 = 0.f, ad1 = 0.f;
        F4(0, am0, ad0) F4(1, am1, ad1)
        F4(2, am0, ad0) F4(3, am1, ad1)
        F4(4, am0, ad0) F4(5, am1, ad1)
        if (u < 4) { F4(6, am0, ad0) }

        float s_ = fmaf(-0.98f, am0 + am1, -0.02f * (ad0 + ad1));
        s_ += __shfl_xor(s_, 1);
        s_ += __shfl_xor(s_, 2);
        s_ += __shfl_xor(s_, 4);
        s_ += __shfl_xor(s_, 8);

        if (u == 0 && cand < NCAND)
            out[(size_t)b * NCAND + cand] = base + s_;
    }
#undef F4
#undef E
}

extern "C" void kernel_launch(void* const* d_in, const int* in_sizes, int n_in,
                              void* d_out, int out_size, void* d_ws, size_t ws_size,
                              hipStream_t stream) {
    const float* ent   = (const float*)d_in[0];
    const float* relc  = (const float*)d_in[1];
    const float* relo  = (const float*)d_in[2];
    const float* onev  = (const float*)d_in[3];
    const int*   pairs = (const int*)d_in[4];
    const int*   cidx  = (const int*)d_in[5];
    float*       out   = (float*)d_out;

    const size_t denB = (size_t)DROWS * DIM * 2;     // 11,606,400 B (16B-aligned)
    const size_t qB   = (size_t)B * DIM * 2;         // 25,600
    const size_t need = denB + 2 * qB + B * sizeof(float);

    if (ws_size >= need) {
        unsigned char* w = (unsigned char*)d_ws;
        uint4*    dense16 = (uint4*)w;
        _Float16* q16     = (_Float16*)(w + denB);
        _Float16* o16     = (_Float16*)(w + denB + qB);
        float*    baseg   = (float*)(w + denB + 2 * qB);

        setup_kernel<<<CVTBLK + B, THREADS, 0, stream>>>(
            ent, relc, relo, onev, pairs, cidx, dense16, q16, o16, baseg);
        score_f16<<<8 * 4 * 32, THREADS, 0, stream>>>(   // 1024 blocks, all-resident
            dense16, (const uint4*)q16, (const uint4*)o16, baseg, out);
    } else {
        score_f32<<<8 * 8 * 32, THREADS, 0, stream>>>(   // 2048 blocks
            ent, relc, relo, onev, pairs, cidx, out);
    }
}